// Round 9
// baseline (105.277 us; speedup 1.0000x reference)
//
#include <hip/hip_runtime.h>
#include <hip/hip_bf16.h>
#include <hip/hip_fp8.h>

// Problem constants (features: (16, 1024, 512) fp32)
#define B_ 16
#define T_ 1024
#define D_ 512
#define EPS_ 1e-8f
#define SCALE2 20.609929155566063f   // (1/0.07) * log2(e): logits in base-2 domain
#define LN2_ 0.6931471805599453f

#define BM 128
#define BN 128
#define NKIT 4                       // D_/128: K=128 fp8 per kit
#define SCL 0x7B7B7B7B               // E8M0 2^-4 in every byte (opsel-immune)

typedef __attribute__((ext_vector_type(4))) int   int4v;
typedef __attribute__((ext_vector_type(8))) int   int8v;
typedef __attribute__((ext_vector_type(4))) float floatx4;

typedef __attribute__((address_space(1))) const unsigned int g_u32;
typedef __attribute__((address_space(3))) unsigned int l_u32;

__device__ __forceinline__ void glds16(const void* g, void* l) {
    __builtin_amdgcn_global_load_lds((g_u32*)g, (l_u32*)l, 16, 0, 0);
}

__device__ __forceinline__ unsigned char f2e4m3(float x) {
    __hip_fp8_e4m3 q(x);                       // OCP e4m3fn (r8-proven)
    return (unsigned char)q.__x;
}

// ---------------- row L2-normalize -> fp8 e4m3 (x16), fused zero-init --------
// (r8-proven) Stores 16*n_i; MFMA block-scales 2^-4 * 2^-4 restore the product.
__global__ __launch_bounds__(256) void norm_kernel(const float* __restrict__ f,
                                                   unsigned char* __restrict__ nrm,
                                                   float* __restrict__ rs_g,
                                                   float* __restrict__ rp_g,
                                                   float* __restrict__ out) {
    const int gi = blockIdx.x * 256 + threadIdx.x;
    if (gi < B_ * T_) { rs_g[gi] = 0.0f; rp_g[gi] = 0.0f; }
    if (gi == 0) out[0] = 0.0f;

    const int row  = blockIdx.x * 4 + (threadIdx.x >> 6);
    const int lane = threadIdx.x & 63;
    const size_t off = (size_t)row * D_ + lane * 8;
    const float4 v0 = *(const float4*)(f + off);
    const float4 v1 = *(const float4*)(f + off + 4);
    float ss = v0.x*v0.x + v0.y*v0.y + v0.z*v0.z + v0.w*v0.w
             + v1.x*v1.x + v1.y*v1.y + v1.z*v1.z + v1.w*v1.w;
    #pragma unroll
    for (int o = 32; o >= 1; o >>= 1) ss += __shfl_xor(ss, o, 64);
    const float sc = 16.0f / fmaxf(sqrtf(ss), EPS_);
    unsigned int w0 =  (unsigned int)f2e4m3(v0.x*sc)
                    | ((unsigned int)f2e4m3(v0.y*sc) << 8)
                    | ((unsigned int)f2e4m3(v0.z*sc) << 16)
                    | ((unsigned int)f2e4m3(v0.w*sc) << 24);
    unsigned int w1 =  (unsigned int)f2e4m3(v1.x*sc)
                    | ((unsigned int)f2e4m3(v1.y*sc) << 8)
                    | ((unsigned int)f2e4m3(v1.z*sc) << 16)
                    | ((unsigned int)f2e4m3(v1.w*sc) << 24);
    uint2 w; w.x = w0; w.y = w1;
    *(uint2*)(nrm + (size_t)row * D_ + lane * 8) = w;
}

// ---------------- MX-fp8 MFMA sim-GEMM: 128x128/block, dbuf LDS --------------
// r6's proven shape (4 waves, dbuf, issue-after-barrier) + r8's proven fp8 MX
// math. Slabs [128 rows][128 B] (K=128/kit), NKIT=4 -> 4 barriers/block.
// Swizzle for 128-B rows (every row starts at bank 0): phys 16B-chunk =
// logical ^ ((row>>1)&3). Staging instr i of wave w writes rows w*32+i*8+(l>>3),
// phys chunk l&7, fetching global chunk (l&7)^((l>>4)&3) — key ((row)>>1)&3
// reduces to (l>>4)&3 since w*32, i*8 are 0 mod 4 after >>1.
// Frag read lane (kq=l>>4, m=l&15): phys p0=(2kq)^((m>>1)&3), p1=p0^1;
// per-b128 the 64 lanes hit each of the 8 bank-quads exactly 8x (balanced).
__global__ __launch_bounds__(256, 2) void loss_kernel(const unsigned char* __restrict__ nrm,
                                                      float* __restrict__ rs_g,
                                                      float* __restrict__ rp_g) {
    const int b  = blockIdx.y;
    const int t0 = blockIdx.x * BM;
    const int j0 = blockIdx.z * BN;
    const char* base = (const char*)(nrm + (size_t)b * T_ * D_);  // row = 512 B

    __shared__ __align__(16) char Al[2][16384];   // [128 rows][128 B] x 2 phases
    __shared__ __align__(16) char Bl[2][16384];   // 64 KB total -> 2 blocks/CU

    const int tid = threadIdx.x;
    const int w   = tid >> 6;
    const int l   = tid & 63;

    // ---- staging addressing (write-side swizzle)
    const int r8l = l >> 3;                       // row-in-group 0..7
    const int gch = (l & 7) ^ ((l >> 4) & 3);     // source chunk for phys l&7
    const char* sA[4];
    const char* sB[4];
    #pragma unroll
    for (int i = 0; i < 4; ++i) {
        sA[i] = base + (size_t)(t0 + w * 32 + i * 8 + r8l) * 512 + gch * 16;
        sB[i] = base + (size_t)(j0 + w * 32 + i * 8 + r8l) * 512 + gch * 16;
    }

#define ISSUE(P, KIT) do {                                                \
    _Pragma("unroll")                                                     \
    for (int i_ = 0; i_ < 4; ++i_) {                                      \
        glds16(sA[i_] + (KIT) * 128, (char*)Al[P] + w * 4096 + i_ * 1024);\
        glds16(sB[i_] + (KIT) * 128, (char*)Bl[P] + w * 4096 + i_ * 1024);\
    }                                                                     \
} while (0)

    // ---- fragment read addressing (read-side swizzle)
    const int wr = w >> 1, wc = w & 1;            // 64x64 quadrant per wave
    const int m  = l & 15;
    const int kq = l >> 4;
    const int p0 = (2 * kq) ^ ((m >> 1) & 3);
    const int rd0 = m * 128 + p0 * 16;
    const int rd1 = m * 128 + (p0 ^ 1) * 16;

    floatx4 acc[4][4] = {};

    ISSUE(0, 0);   // prologue: kit 0 in flight

    #pragma unroll
    for (int kit = 0; kit < NKIT; ++kit) {
        __syncthreads();                          // drains only the 1-kit-old DMAs
        if (kit + 1 < NKIT) ISSUE((kit + 1) & 1, kit + 1);

        const char* As = (const char*)Al[kit & 1] + wr * 8192;
        const char* Bs = (const char*)Bl[kit & 1] + wc * 8192;
        int8v af[4], bf[4];
        #pragma unroll
        for (int mi = 0; mi < 4; ++mi) {
            int4v lo = *(const int4v*)(As + mi * 2048 + rd0);
            int4v hi = *(const int4v*)(As + mi * 2048 + rd1);
            af[mi] = __builtin_shufflevector(lo, hi, 0, 1, 2, 3, 4, 5, 6, 7);
        }
        #pragma unroll
        for (int ni = 0; ni < 4; ++ni) {
            int4v lo = *(const int4v*)(Bs + ni * 2048 + rd0);
            int4v hi = *(const int4v*)(Bs + ni * 2048 + rd1);
            bf[ni] = __builtin_shufflevector(lo, hi, 0, 1, 2, 3, 4, 5, 6, 7);
        }

        #pragma unroll
        for (int mi = 0; mi < 4; ++mi)
            #pragma unroll
            for (int ni = 0; ni < 4; ++ni)
                acc[mi][ni] = __builtin_amdgcn_mfma_scale_f32_16x16x128_f8f6f4(
                    af[mi], bf[ni], acc[mi][ni],
                    0, 0,              // cbsz/blgp = fp8 e4m3
                    0, SCL, 0, SCL);   // scales 2^-4 (r8-proven)
    }
#undef ISSUE

    // Epilogue (r6-proven). C/D layout: col = lane&15, row = (lane>>4)*4 + reg.
    const int lrow = l >> 4;
    const int lcol = l & 15;
    const int bT   = b * T_;

    #pragma unroll
    for (int mi = 0; mi < 4; ++mi) {
        #pragma unroll
        for (int rg = 0; rg < 4; ++rg) {
            const int t = t0 + wr * 64 + mi * 16 + lrow * 4 + rg;
            float rsum = 0.f, rp = 0.f;
            #pragma unroll
            for (int ni = 0; ni < 4; ++ni) {
                const int j  = j0 + wc * 64 + ni * 16 + lcol;
                const float s2 = acc[mi][ni][rg] * SCALE2;      // base-2 logit
                const float e  = exp2f(s2);
                if (j < t - 1 || j > t + 1) rsum += e;          // negatives only
                if (j == t + 1)             rp   = s2;          // positive logit
            }
            #pragma unroll
            for (int o = 8; o >= 1; o >>= 1) {
                rsum += __shfl_xor(rsum, o, 64);
                rp   += __shfl_xor(rp,   o, 64);
            }
            if (lcol == 0) {
                atomicAdd(&rs_g[bT + t], rsum);
                if (rp != 0.0f) atomicAdd(&rp_g[bT + t], rp);
            }
        }
    }
}

// ---------------- finalize: loss per (b,t), mean (base-2 domain) -------------
__global__ __launch_bounds__(256) void fin_kernel(const float* __restrict__ rs_g,
                                                  const float* __restrict__ rp_g,
                                                  float* __restrict__ out) {
    const int idx = blockIdx.x * 256 + threadIdx.x;
    float v = 0.0f;
    if (idx < B_ * T_) {
        const int t = idx & (T_ - 1);
        if (t >= 1 && t <= T_ - 2) {
            const float p2 = rp_g[idx];           // pos logit * log2e
            const float s  = rs_g[idx];           // sum_neg 2^logit2
            v = (log2f(exp2f(p2) + s) - p2) * LN2_;
        }
    }
    #pragma unroll
    for (int o = 32; o >= 1; o >>= 1) v += __shfl_xor(v, o, 64);
    __shared__ float ws_[4];
    if ((threadIdx.x & 63) == 0) ws_[threadIdx.x >> 6] = v;
    __syncthreads();
    if (threadIdx.x == 0) {
        const float scale = 1.0f / (float)(B_ * (T_ - 2));
        atomicAdd(out, (ws_[0] + ws_[1] + ws_[2] + ws_[3]) * scale);
    }
}

extern "C" void kernel_launch(void* const* d_in, const int* in_sizes, int n_in,
                              void* d_out, int out_size, void* d_ws, size_t ws_size,
                              hipStream_t stream) {
    const float* feat = (const float*)d_in[0];
    float* out = (float*)d_out;

    // ws layout: nrm (fp8, B*T*D bytes = 8 MB) | rs (B*T f32) | rp (B*T f32)
    unsigned char* nrm = (unsigned char*)d_ws;
    float* rs_g = (float*)((char*)d_ws + (size_t)B_ * T_ * D_);
    float* rp_g = rs_g + B_ * T_;

    norm_kernel<<<B_ * T_ / 4, 256, 0, stream>>>(feat, nrm, rs_g, rp_g, out);
    loss_kernel<<<dim3(T_ / BM, B_, T_ / BN), 256, 0, stream>>>(nrm, rs_g, rp_g);
    fin_kernel<<<(B_ * T_ + 255) / 256, 256, 0, stream>>>(rs_g, rp_g, out);
}